// Round 1
// baseline (134.076 us; speedup 1.0000x reference)
//
#include <hip/hip_runtime.h>
#include <math.h>

// Problem constants (from reference setup_inputs)
#define NN 256   // nodes
#define FF 256   // feature dim
#define BB 32    // batch
#define EE 8192  // edges (N * DEG)

#define BGROUPS 2                 // grid.y; batches per block = BB/BGROUPS = 16
#define CHUNK 64                  // edges staged in LDS per chunk

// ---------------------------------------------------------------------------
// Kernel 1: build dst-CSR + per-node 1/max(out-degree,1), single block.
// LDS histogram of dst -> serial scan -> LDS-cursor scatter of edge ids.
// ---------------------------------------------------------------------------
__global__ __launch_bounds__(1024) void build_csr_kernel(
    const int* __restrict__ src, const int* __restrict__ dst,
    int* __restrict__ offsets,      // [NN+1]
    int* __restrict__ edge_ids,     // [EE]
    float* __restrict__ rnorm)      // [NN]
{
    __shared__ int h[NN];       // dst histogram
    __shared__ int hs[NN];      // src histogram (for norm)
    __shared__ int off[NN + 1];
    __shared__ int cur[NN];

    const int tid = threadIdx.x;
    const int nt  = blockDim.x;

    for (int i = tid; i < NN; i += nt) { h[i] = 0; hs[i] = 0; }
    __syncthreads();

    for (int e = tid; e < EE; e += nt) {
        atomicAdd(&h[dst[e]], 1);
        atomicAdd(&hs[src[e]], 1);
    }
    __syncthreads();

    if (tid == 0) {
        int a = 0;
        for (int i = 0; i < NN; i++) { off[i] = a; a += h[i]; }
        off[NN] = a;
    }
    __syncthreads();

    for (int i = tid; i < NN; i += nt) cur[i] = off[i];
    __syncthreads();

    for (int e = tid; e < EE; e += nt) {
        int p = atomicAdd(&cur[dst[e]], 1);
        edge_ids[p] = e;
    }

    for (int i = tid; i < NN + 1; i += nt) offsets[i] = off[i];
    for (int i = tid; i < NN; i += nt)
        rnorm[i] = 1.0f / fmaxf((float)hs[i], 1.0f);
}

// ---------------------------------------------------------------------------
// Kernel 2: per-destination gather-accumulate.
// Block = (d, bgroup). 256 threads = 4 batch-subgroups x 64 float4 f-slices.
// Each thread: 4 batches x float4 = 16 accumulator floats in registers.
// W[s,d,:] loaded once per thread per edge, reused across 4 batches.
// ---------------------------------------------------------------------------
__device__ __forceinline__ void fma4(float4& a, const float4 x, const float4 w) {
    a.x = fmaf(x.x, w.x, a.x);
    a.y = fmaf(x.y, w.y, a.y);
    a.z = fmaf(x.z, w.z, a.z);
    a.w = fmaf(x.w, w.w, a.w);
}

__global__ __launch_bounds__(256) void propagate_kernel(
    const float4* __restrict__ nf4,    // [BB, NN, FF/4]
    const float4* __restrict__ W4,     // [NN, NN, FF/4]
    const float*  __restrict__ phase,  // [NN, NN]
    const int*    __restrict__ src,    // [EE]
    const int*    __restrict__ offsets,
    const int*    __restrict__ edge_ids,
    const float*  __restrict__ rnorm,
    float4*       __restrict__ out4)   // [BB, NN, FF/4]
{
    const int d     = blockIdx.x;
    const int b0    = blockIdx.y * (BB / BGROUPS);
    const int tf    = threadIdx.x & 63;    // float4 index within F
    const int bsub  = threadIdx.x >> 6;    // 0..3
    const int bbase = b0 + bsub * 4;       // this thread's 4 batches

    __shared__ int   s_s[CHUNK];
    __shared__ float s_c[CHUNK];

    const int beg = offsets[d];
    const int end = offsets[d + 1];

    float4 acc0 = {0.f, 0.f, 0.f, 0.f};
    float4 acc1 = {0.f, 0.f, 0.f, 0.f};
    float4 acc2 = {0.f, 0.f, 0.f, 0.f};
    float4 acc3 = {0.f, 0.f, 0.f, 0.f};

    for (int base = beg; base < end; base += CHUNK) {
        const int m = min(CHUNK, end - base);
        __syncthreads();   // protect LDS reuse across chunks (no-op cost on first)
        if (threadIdx.x < m) {
            const int e = edge_ids[base + threadIdx.x];
            const int s = src[e];
            s_s[threadIdx.x] = s;
            s_c[threadIdx.x] = cosf(phase[s * NN + d]);
        }
        __syncthreads();

        for (int k = 0; k < m; k++) {
            const int   s = s_s[k];
            const float c = s_c[k];
            float4 w = W4[(s * NN + d) * (FF / 4) + tf];
            w.x *= c; w.y *= c; w.z *= c; w.w *= c;
            const float4 x0 = nf4[((bbase + 0) * NN + s) * (FF / 4) + tf];
            const float4 x1 = nf4[((bbase + 1) * NN + s) * (FF / 4) + tf];
            const float4 x2 = nf4[((bbase + 2) * NN + s) * (FF / 4) + tf];
            const float4 x3 = nf4[((bbase + 3) * NN + s) * (FF / 4) + tf];
            fma4(acc0, x0, w);
            fma4(acc1, x1, w);
            fma4(acc2, x2, w);
            fma4(acc3, x3, w);
        }
    }

    const float rn = rnorm[d];
    float4 o;
    o.x = acc0.x * rn; o.y = acc0.y * rn; o.z = acc0.z * rn; o.w = acc0.w * rn;
    out4[((bbase + 0) * NN + d) * (FF / 4) + tf] = o;
    o.x = acc1.x * rn; o.y = acc1.y * rn; o.z = acc1.z * rn; o.w = acc1.w * rn;
    out4[((bbase + 1) * NN + d) * (FF / 4) + tf] = o;
    o.x = acc2.x * rn; o.y = acc2.y * rn; o.z = acc2.z * rn; o.w = acc2.w * rn;
    out4[((bbase + 2) * NN + d) * (FF / 4) + tf] = o;
    o.x = acc3.x * rn; o.y = acc3.y * rn; o.z = acc3.z * rn; o.w = acc3.w * rn;
    out4[((bbase + 3) * NN + d) * (FF / 4) + tf] = o;
}

// ---------------------------------------------------------------------------
// Launch
// ---------------------------------------------------------------------------
extern "C" void kernel_launch(void* const* d_in, const int* in_sizes, int n_in,
                              void* d_out, int out_size, void* d_ws, size_t ws_size,
                              hipStream_t stream) {
    const float* nf    = (const float*)d_in[0];   // [B,N,F]
    const float* W     = (const float*)d_in[1];   // [N,N,F]
    const float* phase = (const float*)d_in[2];   // [N,N]
    const int*   src   = (const int*)d_in[3];     // [E]
    const int*   dst   = (const int*)d_in[4];     // [E]
    float*       out   = (float*)d_out;           // [B,N,F]

    // Workspace layout (ints): offsets[257] | pad | edge_ids[8192] | rnorm[256]
    int*   wsI      = (int*)d_ws;
    int*   offsets  = wsI;               // 257 ints
    int*   edge_ids = wsI + 272;         // 8192 ints (16B-aligned start)
    float* rnorm    = (float*)(wsI + 272 + EE);  // 256 floats

    build_csr_kernel<<<1, 1024, 0, stream>>>(src, dst, offsets, edge_ids, rnorm);

    dim3 grid(NN, BGROUPS);
    propagate_kernel<<<grid, 256, 0, stream>>>(
        (const float4*)nf, (const float4*)W, phase, src,
        offsets, edge_ids, rnorm, (float4*)out);
}

// Round 2
// 127.656 us; speedup vs baseline: 1.0503x; 1.0503x over previous
//
#include <hip/hip_runtime.h>
#include <math.h>

// Problem constants (from reference setup_inputs)
#define NN 256   // nodes
#define FF 256   // feature dim
#define BB 32    // batch
#define EE 8192  // edges (N * DEG)

#define BGROUPS 2      // grid.y; batches per block = BB/BGROUPS = 16
#define CAP 1024       // max supported in-degree (bench max ~55; random dst, mean 32)

// ---------------------------------------------------------------------------
// Single fused kernel. Block = (d, bgroup), 256 threads.
//   Phase 1: scan all E edges (int4 coalesced), append (s, cos(phase[s,d]))
//            to an LDS list for dst==d; count src==d for the norm.
//   Phase 2: pad list to multiple of 4 (s=0,c=0 dummies are exact no-ops),
//            unroll-4 gather-accumulate: per iter 4 W float4 + 16 nf float4
//            loads in flight -> MLP covers L2/L3 latency at low occupancy.
// Threads: tf = float4-slice of F (64), bsub = batch subgroup (4), each
// thread accumulates 4 batches x float4 = 16 floats in registers.
// ---------------------------------------------------------------------------
__device__ __forceinline__ void fma4(float4& a, const float4 x, const float4 w) {
    a.x = fmaf(x.x, w.x, a.x);
    a.y = fmaf(x.y, w.y, a.y);
    a.z = fmaf(x.z, w.z, a.z);
    a.w = fmaf(x.w, w.w, a.w);
}

__global__ __launch_bounds__(256) void fused_propagate_kernel(
    const float4* __restrict__ nf4,    // [BB, NN, FF/4]
    const float4* __restrict__ W4,     // [NN, NN, FF/4]
    const float*  __restrict__ phase,  // [NN, NN]
    const int*    __restrict__ src,    // [EE]
    const int*    __restrict__ dst,    // [EE]
    float4*       __restrict__ out4)   // [BB, NN, FF/4]
{
    const int d     = blockIdx.x;
    const int tid   = threadIdx.x;
    const int tf    = tid & 63;            // float4 index within F
    const int bsub  = tid >> 6;            // 0..3
    const int bbase = blockIdx.y * (BB / BGROUPS) + bsub * 4;

    __shared__ int   ls[CAP];
    __shared__ float lc[CAP];
    __shared__ int   s_cnt;      // matched-edge append cursor
    __shared__ int   s_srccnt;   // # edges with src == d (out-degree of node d)
    __shared__ int   s_n;        // padded list length

    if (tid == 0) { s_cnt = 0; s_srccnt = 0; }
    __syncthreads();

    // ---- Phase 1: coalesced edge scan ----
    const int4* dst4 = (const int4*)dst;
    const int4* src4 = (const int4*)src;
    int mysrc = 0;
    for (int i = tid; i < EE / 4; i += 256) {
        const int4 dv = dst4[i];
        const int4 sv = src4[i];
        if (dv.x == d) { int p = atomicAdd(&s_cnt, 1); if (p < CAP) { ls[p] = sv.x; lc[p] = cosf(phase[sv.x * NN + d]); } }
        if (dv.y == d) { int p = atomicAdd(&s_cnt, 1); if (p < CAP) { ls[p] = sv.y; lc[p] = cosf(phase[sv.y * NN + d]); } }
        if (dv.z == d) { int p = atomicAdd(&s_cnt, 1); if (p < CAP) { ls[p] = sv.z; lc[p] = cosf(phase[sv.z * NN + d]); } }
        if (dv.w == d) { int p = atomicAdd(&s_cnt, 1); if (p < CAP) { ls[p] = sv.w; lc[p] = cosf(phase[sv.w * NN + d]); } }
        mysrc += (sv.x == d) + (sv.y == d) + (sv.z == d) + (sv.w == d);
    }
    if (mysrc) atomicAdd(&s_srccnt, mysrc);
    __syncthreads();

    // ---- pad list to multiple of 4 with exact no-op edges ----
    if (tid == 0) {
        int n  = min(s_cnt, CAP);
        int n4 = (n + 3) & ~3;
        for (int i = n; i < n4; i++) { ls[i] = 0; lc[i] = 0.0f; }
        s_n = n4;
    }
    __syncthreads();

    const int   nlist = s_n;
    const float rn    = 1.0f / fmaxf((float)s_srccnt, 1.0f);

    // ---- Phase 2: unroll-4 gather-accumulate ----
    float4 acc0 = {0.f, 0.f, 0.f, 0.f};
    float4 acc1 = {0.f, 0.f, 0.f, 0.f};
    float4 acc2 = {0.f, 0.f, 0.f, 0.f};
    float4 acc3 = {0.f, 0.f, 0.f, 0.f};

    const int woff = d * (FF / 4) + tf;       // W4 offset for (d, tf)
    const int nfo0 = (bbase + 0) * NN * (FF / 4) + tf;
    const int nfo1 = (bbase + 1) * NN * (FF / 4) + tf;
    const int nfo2 = (bbase + 2) * NN * (FF / 4) + tf;
    const int nfo3 = (bbase + 3) * NN * (FF / 4) + tf;

    for (int k = 0; k < nlist; k += 4) {
        const int   s0 = ls[k + 0], s1 = ls[k + 1], s2 = ls[k + 2], s3 = ls[k + 3];
        const float c0 = lc[k + 0], c1 = lc[k + 1], c2 = lc[k + 2], c3 = lc[k + 3];

        float4 w0 = W4[s0 * (NN * FF / 4) + woff];
        float4 w1 = W4[s1 * (NN * FF / 4) + woff];
        float4 w2 = W4[s2 * (NN * FF / 4) + woff];
        float4 w3 = W4[s3 * (NN * FF / 4) + woff];

        const float4 x00 = nf4[nfo0 + s0 * (FF / 4)];
        const float4 x01 = nf4[nfo1 + s0 * (FF / 4)];
        const float4 x02 = nf4[nfo2 + s0 * (FF / 4)];
        const float4 x03 = nf4[nfo3 + s0 * (FF / 4)];
        const float4 x10 = nf4[nfo0 + s1 * (FF / 4)];
        const float4 x11 = nf4[nfo1 + s1 * (FF / 4)];
        const float4 x12 = nf4[nfo2 + s1 * (FF / 4)];
        const float4 x13 = nf4[nfo3 + s1 * (FF / 4)];
        const float4 x20 = nf4[nfo0 + s2 * (FF / 4)];
        const float4 x21 = nf4[nfo1 + s2 * (FF / 4)];
        const float4 x22 = nf4[nfo2 + s2 * (FF / 4)];
        const float4 x23 = nf4[nfo3 + s2 * (FF / 4)];
        const float4 x30 = nf4[nfo0 + s3 * (FF / 4)];
        const float4 x31 = nf4[nfo1 + s3 * (FF / 4)];
        const float4 x32 = nf4[nfo2 + s3 * (FF / 4)];
        const float4 x33 = nf4[nfo3 + s3 * (FF / 4)];

        w0.x *= c0; w0.y *= c0; w0.z *= c0; w0.w *= c0;
        w1.x *= c1; w1.y *= c1; w1.z *= c1; w1.w *= c1;
        w2.x *= c2; w2.y *= c2; w2.z *= c2; w2.w *= c2;
        w3.x *= c3; w3.y *= c3; w3.z *= c3; w3.w *= c3;

        fma4(acc0, x00, w0); fma4(acc1, x01, w0); fma4(acc2, x02, w0); fma4(acc3, x03, w0);
        fma4(acc0, x10, w1); fma4(acc1, x11, w1); fma4(acc2, x12, w1); fma4(acc3, x13, w1);
        fma4(acc0, x20, w2); fma4(acc1, x21, w2); fma4(acc2, x22, w2); fma4(acc3, x23, w2);
        fma4(acc0, x30, w3); fma4(acc1, x31, w3); fma4(acc2, x32, w3); fma4(acc3, x33, w3);
    }

    // ---- epilogue: normalize + store ----
    const int oo = d * (FF / 4) + tf;
    float4 o;
    o.x = acc0.x * rn; o.y = acc0.y * rn; o.z = acc0.z * rn; o.w = acc0.w * rn;
    out4[(bbase + 0) * NN * (FF / 4) + oo] = o;
    o.x = acc1.x * rn; o.y = acc1.y * rn; o.z = acc1.z * rn; o.w = acc1.w * rn;
    out4[(bbase + 1) * NN * (FF / 4) + oo] = o;
    o.x = acc2.x * rn; o.y = acc2.y * rn; o.z = acc2.z * rn; o.w = acc2.w * rn;
    out4[(bbase + 2) * NN * (FF / 4) + oo] = o;
    o.x = acc3.x * rn; o.y = acc3.y * rn; o.z = acc3.z * rn; o.w = acc3.w * rn;
    out4[(bbase + 3) * NN * (FF / 4) + oo] = o;
}

// ---------------------------------------------------------------------------
// Launch: ONE kernel, no workspace needed.
// ---------------------------------------------------------------------------
extern "C" void kernel_launch(void* const* d_in, const int* in_sizes, int n_in,
                              void* d_out, int out_size, void* d_ws, size_t ws_size,
                              hipStream_t stream) {
    const float* nf    = (const float*)d_in[0];   // [B,N,F]
    const float* W     = (const float*)d_in[1];   // [N,N,F]
    const float* phase = (const float*)d_in[2];   // [N,N]
    const int*   src   = (const int*)d_in[3];     // [E]
    const int*   dst   = (const int*)d_in[4];     // [E]
    float*       out   = (float*)d_out;           // [B,N,F]

    dim3 grid(NN, BGROUPS);
    fused_propagate_kernel<<<grid, 256, 0, stream>>>(
        (const float4*)nf, (const float4*)W, phase, src, dst, (float4*)out);
}